// Round 18
// baseline (1093.212 us; speedup 1.0000x reference)
//
#include <hip/hip_runtime.h>
#include <hip/hip_bf16.h>

// PhiNet: per-point MLP 16->128->128->64 (ReLU) + segment mean (4096 segs x 256 pts).
// R15 post-mortem: allocator fit 64 VGPR by parking h3[64] in AGPRs; fold phase paid
// ~16K v_accvgpr RMW/pt (23% of issue). R16: batch fold into k-halved VGPR accs h3h[32],
// touching AGPR h3 only 64x per quarter (16K -> ~0.8K moves/pt). Fold live set:
// acc[32]+h3h[32]=64 VGPR + h3[64 AGPR] = 128 unified -> keeps 4 waves/EU bucket.

#define THREADS 256

// ---- one-shot prep: W2 [128][128] -> W2t[i][o]; W3 [64][128] -> W3t[o][k] ----
__global__ void transpose_w(const float* __restrict__ W2, const float* __restrict__ W3,
                            float* __restrict__ W2t, float* __restrict__ W3t) {
    int idx = blockIdx.x * blockDim.x + threadIdx.x;     // 0 .. 16383
    if (idx < 128 * 128) {
        int o = idx >> 7, i = idx & 127;
        W2t[i * 128 + o] = W2[o * 128 + i];
    }
    if (idx < 64 * 128) {
        int k = idx >> 7, o = idx & 127;
        W3t[o * 64 + k] = W3[k * 128 + o];
    }
}

__global__ __launch_bounds__(THREADS)
void phinet_kernel(const float* __restrict__ x,
                   const float* __restrict__ W1, const float* __restrict__ b1,
                   const float* __restrict__ W2t, const float* __restrict__ b2,
                   const float* __restrict__ W3t, const float* __restrict__ b3,
                   const int*   __restrict__ seg,
                   float* __restrict__ out, int N)
{
    const int s     = blockIdx.x;
    const int tid   = threadIdx.x;
    const int lane  = tid & 63;
    const int wave  = tid >> 6;
    const int start = seg[s];
    const int end   = seg[s + 1];

    __shared__ float partial[4][64];
    partial[wave][lane] = 0.0f;
    __syncthreads();

    for (int p = start + tid; p < end; p += THREADS) {
        // ---- point features (coalesced per channel: lane-consecutive p) ----
        float xv[16];
#pragma unroll
        for (int c = 0; c < 16; ++c)
            xv[c] = x[(size_t)c * (size_t)N + (size_t)p];

        // ---- h3 accumulators (expect AGPR-resident; touched 64x per quarter) ----
        float h3[64];
#pragma unroll
        for (int k = 0; k < 64; ++k) h3[k] = b3[k];

        // ---- o-quarters: L1+L2 fused over i, then k-halved fold through W3 ----
        for (int q = 0; q < 4; ++q) {                 // runtime loop (I$ size)
            const float* W2tq = W2t + q * 32;         // slice base (SGPR)
            const float* bq   = b2  + q * 32;
            float acc[32];
#pragma unroll
            for (int t = 0; t < 32; ++t) acc[t] = bq[t];

#pragma unroll 2
            for (int i = 0; i < 128; ++i) {
                // h1_i = relu(b1[i] + W1[i,:] . xv)   (W1 row: wave-uniform s_load)
                float a = b1[i];
#pragma unroll
                for (int c = 0; c < 16; ++c)
                    a = fmaf(W1[i * 16 + c], xv[c], a);
                const float h1i = fmaxf(a, 0.0f);
                // acc[t] += W2t[i][q*32+t] * h1_i   (32 contiguous floats: s_load)
#pragma unroll
                for (int t = 0; t < 32; ++t)
                    acc[t] = fmaf(W2tq[i * 128 + t], h1i, acc[t]);
            }

            // fold quarter into h3, k-halved: h3h[32] in VGPRs, h3 RMW once per (q,kh)
#pragma unroll
            for (int kh = 0; kh < 2; ++kh) {
                float h3h[32];
#pragma unroll
                for (int k = 0; k < 32; ++k) h3h[k] = 0.0f;
#pragma unroll
                for (int t = 0; t < 32; ++t) {
                    const float h2 = fmaxf(acc[t], 0.0f);          // cheap recompute
                    const float* w3row = W3t + (q * 32 + t) * 64 + kh * 32; // 32 contig
#pragma unroll
                    for (int k = 0; k < 32; ++k)
                        h3h[k] = fmaf(w3row[k], h2, h3h[k]);
                }
#pragma unroll
                for (int k = 0; k < 32; ++k)
                    h3[kh * 32 + k] += h3h[k];        // 32 AGPR RMW per (q,kh)
            }
        }

        // ---- per-wave butterfly reduce each of the 64 features ----
#pragma unroll
        for (int k = 0; k < 64; ++k) {
            float v = fmaxf(h3[k], 0.0f);             // final ReLU, then mean
            v += __shfl_xor(v, 1);
            v += __shfl_xor(v, 2);
            v += __shfl_xor(v, 4);
            v += __shfl_xor(v, 8);
            v += __shfl_xor(v, 16);
            v += __shfl_xor(v, 32);
            if (lane == 0) partial[wave][k] += v;
        }
    }

    __syncthreads();

    // ---- final cross-wave reduce + mean, one thread per feature ----
    if (tid < 64) {
        const float cnt = (float)(end - start);
        float v = partial[0][tid] + partial[1][tid] + partial[2][tid] + partial[3][tid];
        out[(size_t)s * 64 + tid] = v / cnt;
    }
}

extern "C" void kernel_launch(void* const* d_in, const int* in_sizes, int n_in,
                              void* d_out, int out_size, void* d_ws, size_t ws_size,
                              hipStream_t stream) {
    const float* x  = (const float*)d_in[0];
    const float* W1 = (const float*)d_in[1];
    const float* b1 = (const float*)d_in[2];
    const float* W2 = (const float*)d_in[3];
    const float* b2 = (const float*)d_in[4];
    const float* W3 = (const float*)d_in[5];
    const float* b3 = (const float*)d_in[6];
    const int*  seg = (const int*)d_in[7];
    float* out = (float*)d_out;

    const int N = in_sizes[0] / 16;          // x is [1, 16, N]
    const int S = in_sizes[7] - 1;           // sample_indices has S+1 entries

    float* W2t = (float*)d_ws;               // 128*128*4 = 64 KB
    float* W3t = W2t + 128 * 128;            // 128*64*4  = 32 KB

    transpose_w<<<(128 * 128 + 255) / 256, 256, 0, stream>>>(W2, W3, W2t, W3t);
    phinet_kernel<<<S, THREADS, 0, stream>>>(x, W1, b1, W2t, b2, W3t, b3, seg, out, N);
}